// Round 9
// baseline (129.683 us; speedup 1.0000x reference)
//
#include <hip/hip_runtime.h>
#include <cmath>

#define NPIX 16384
#define NATOM 1024
#define DIM 64
#define SPAR 8

// ---------------------------------------------------------------------------
// Fused pre-pass, grid-partitioned (1344 blocks):
//   [0,256):    G 64x64 tile (bi,bj) = D^T D + 1e-4 I, fp64 acc (LDS-staged,
//               ascending-d order -> bit-identical to prior rounds); Gd diag
//   [256,320):  Dt transpose (each block 1024 contiguous D elems)
//   [320,1344): HB 128n x 128k tile (fp32, 8x8/thread)
// ---------------------------------------------------------------------------
__global__ __launch_bounds__(256) void k_pre(const float* __restrict__ X,
                                             const float* __restrict__ D,
                                             float* __restrict__ G,
                                             float* __restrict__ Dt,
                                             float* __restrict__ Gd,
                                             float* __restrict__ HB) {
  __shared__ float smem[2 * DIM * 128];  // 64 KiB
  const int b = blockIdx.x;
  if (b < 256) {
    // ---- gram tile ----
    const int i0 = (b >> 4) * 64, j0 = (b & 15) * 64;
    float(*sA)[65] = (float(*)[65])smem;                  // D[:, i0..i0+63]
    float(*sB)[65] = (float(*)[65])(smem + DIM * 65);     // D[:, j0..j0+63]
    for (int t = threadIdx.x; t < DIM * 16; t += 256) {
      int d = t >> 4, c4 = (t & 15) * 4;
      *reinterpret_cast<float4*>(&sA[d][c4]) =
          *reinterpret_cast<const float4*>(&D[(size_t)d * NATOM + i0 + c4]);
      *reinterpret_cast<float4*>(&sB[d][c4]) =
          *reinterpret_cast<const float4*>(&D[(size_t)d * NATOM + j0 + c4]);
    }
    __syncthreads();
    const int ty = (threadIdx.x >> 4) * 4;  // row micro-tile
    const int tx = (threadIdx.x & 15) * 4;  // col micro-tile
    double acc[4][4];
#pragma unroll
    for (int ii = 0; ii < 4; ++ii)
#pragma unroll
      for (int jj = 0; jj < 4; ++jj) acc[ii][jj] = 0.0;
    for (int d = 0; d < DIM; ++d) {
      float a[4], bb[4];
#pragma unroll
      for (int ii = 0; ii < 4; ++ii) a[ii] = sA[d][ty + ii];
#pragma unroll
      for (int jj = 0; jj < 4; ++jj) bb[jj] = sB[d][tx + jj];
#pragma unroll
      for (int ii = 0; ii < 4; ++ii)
#pragma unroll
        for (int jj = 0; jj < 4; ++jj)
          acc[ii][jj] += (double)a[ii] * (double)bb[jj];
    }
#pragma unroll
    for (int ii = 0; ii < 4; ++ii)
#pragma unroll
      for (int jj = 0; jj < 4; ++jj) {
        const int k1 = i0 + ty + ii, k2 = j0 + tx + jj;
        float g = (float)acc[ii][jj];
        if (k1 == k2) {
          g += 1e-4f;
          Gd[k1] = g;
        }
        G[(size_t)k1 * NATOM + k2] = g;
      }
  } else if (b < 320) {
    // ---- Dt transpose ----
    const int base = (b - 256) * 1024 + threadIdx.x * 4;
    float4 v = *reinterpret_cast<const float4*>(&D[base]);
    const float vv[4] = {v.x, v.y, v.z, v.w};
#pragma unroll
    for (int e = 0; e < 4; ++e) {
      int idx = base + e;
      Dt[(size_t)(idx & (NATOM - 1)) * DIM + (idx >> 10)] = vv[e];
    }
  } else {
    // ---- HB tile ----
    const int bx = b - 320;
    const int n0 = (bx & 127) * 128, k0 = (bx >> 7) * 128;
    float(*sX)[128] = (float(*)[128])smem;
    float(*sD)[128] = (float(*)[128])(smem + DIM * 128);
    for (int i = threadIdx.x; i < DIM * 32; i += 256) {
      int d = i >> 5, c4 = (i & 31) * 4;
      *reinterpret_cast<float4*>(&sX[d][c4]) =
          *reinterpret_cast<const float4*>(&X[(size_t)d * NPIX + n0 + c4]);
      *reinterpret_cast<float4*>(&sD[d][c4]) =
          *reinterpret_cast<const float4*>(&D[(size_t)d * NATOM + k0 + c4]);
    }
    __syncthreads();
    const int nl = (threadIdx.x & 15) * 8;
    const int kl = (threadIdx.x >> 4) * 8;
    float acc[8][8];
#pragma unroll
    for (int i = 0; i < 8; ++i)
#pragma unroll
      for (int j = 0; j < 8; ++j) acc[i][j] = 0.f;
#pragma unroll 4
    for (int d = 0; d < DIM; ++d) {
      float xv[8], dv[8];
      *reinterpret_cast<float4*>(&xv[0]) = *reinterpret_cast<float4*>(&sX[d][nl]);
      *reinterpret_cast<float4*>(&xv[4]) = *reinterpret_cast<float4*>(&sX[d][nl + 4]);
      *reinterpret_cast<float4*>(&dv[0]) = *reinterpret_cast<float4*>(&sD[d][kl]);
      *reinterpret_cast<float4*>(&dv[4]) = *reinterpret_cast<float4*>(&sD[d][kl + 4]);
#pragma unroll
      for (int i = 0; i < 8; ++i)
#pragma unroll
        for (int j = 0; j < 8; ++j) acc[i][j] = fmaf(xv[i], dv[j], acc[i][j]);
    }
#pragma unroll
    for (int i = 0; i < 8; ++i)
#pragma unroll
      for (int j = 0; j < 2; ++j)
        *reinterpret_cast<float4*>(
            &HB[(size_t)(n0 + nl + i) * NATOM + k0 + kl + j * 4]) =
            *reinterpret_cast<float4*>(&acc[i][j * 4]);
  }
}

// ---------------------------------------------------------------------------
// DPP wave64 max-reduce (VALU latency, no LDS). HW-verified (rounds 6-8).
// ---------------------------------------------------------------------------
template <int CTRL>
__device__ __forceinline__ float dpp_fmax(float x) {
  int s = __builtin_amdgcn_update_dpp(__float_as_int(x), __float_as_int(x),
                                      CTRL, 0xf, 0xf, false);
  return fmaxf(x, __int_as_float(s));
}
__device__ __forceinline__ float wave_max_bcast(float x) {
  x = dpp_fmax<0x111>(x);  // row_shr:1
  x = dpp_fmax<0x112>(x);  // row_shr:2
  x = dpp_fmax<0x114>(x);  // row_shr:4
  x = dpp_fmax<0x118>(x);  // row_shr:8
  x = dpp_fmax<0x142>(x);  // row_bcast:15
  x = dpp_fmax<0x143>(x);  // row_bcast:31
  return __int_as_float(__builtin_amdgcn_readlane(__float_as_int(x), 63));
}

// ---------------------------------------------------------------------------
// Batched OMP: ONE WAVE PER PIXEL, 64-thread blocks, no LDS/barriers.
// Lane owns atoms k = lane*16+j (dwordx4-coalesced G/HB traffic).
// Register policy: NO pinned G rows — selected rows are re-read from L2
// each step in two register-reusing chunks (<=4 rows / 64 VGPRs live), so
// total state fits 3 waves/SIMD (__launch_bounds__(64,3)). Row addresses
// depend only on selI, so loads can issue during the previous step's solve.
// Masking: NaN poison of hb (selected atom loses every future argmax).
// Argmax: exact f32 wave max via DPP; index = ballot+ffs lowest lane with
// sc==M, whose in-lane min-j candidate is the global first occurrence
// (lane-major index order) == np.argmax. hbs/diag via uniform scalar loads.
// Score FMA order (ascending i) identical to all passing rounds.
// ---------------------------------------------------------------------------
template <bool HBWS, bool DTW>
__global__ __launch_bounds__(64, 3) void k_omp(const float* __restrict__ HB,
                                               const float* __restrict__ X,
                                               const float* __restrict__ D,
                                               const float* __restrict__ Dt,
                                               const float* __restrict__ G,
                                               const float* __restrict__ Gd,
                                               float* __restrict__ out) {
  const int lane = threadIdx.x & 63;
  const int lane16 = lane * 16;
  const int n = __builtin_amdgcn_readfirstlane(blockIdx.x);

  float hb[16];
  if (HBWS) {
#pragma unroll
    for (int q = 0; q < 4; ++q) {
      float4 v = *reinterpret_cast<const float4*>(
          &HB[(size_t)n * NATOM + lane16 + q * 4]);
      hb[q * 4 + 0] = v.x; hb[q * 4 + 1] = v.y;
      hb[q * 4 + 2] = v.z; hb[q * 4 + 3] = v.w;
    }
  } else {
    double a[16];
#pragma unroll
    for (int j = 0; j < 16; ++j) a[j] = 0.0;
    for (int d = 0; d < DIM; ++d) {
      float xd = X[(size_t)d * NPIX + n];
#pragma unroll
      for (int j = 0; j < 16; ++j)
        a[j] += (double)xd * (double)D[(size_t)d * NATOM + lane16 + j];
    }
#pragma unroll
    for (int j = 0; j < 16; ++j) hb[j] = (float)a[j];
  }
#pragma unroll
  for (int j = 0; j < 16; ++j) asm volatile("" : "+v"(hb[j]));

  int selI[SPAR];  // wave-uniform -> SGPRs
  float Lm[SPAR][SPAR], invL[SPAR], ysel[SPAR], coefF[SPAR];

#pragma unroll 8
  for (int s = 0; s < SPAR; ++s) {
    // ---- h = hb - sum_i coef_i * G[selI_i] (ascending i, chunked rows) ----
    float h[16];
#pragma unroll
    for (int j = 0; j < 16; ++j) h[j] = hb[j];
    {
      float r0[4][16];
      // chunk 0: rows 0..3 (loads depend only on selI -> issue early)
#pragma unroll
      for (int i = 0; i < 4; ++i)
        if (i < s) {
#pragma unroll
          for (int q = 0; q < 4; ++q) {
            float4 rv = *reinterpret_cast<const float4*>(
                &G[(size_t)selI[i] * NATOM + lane16 + q * 4]);
            r0[i][q * 4 + 0] = rv.x; r0[i][q * 4 + 1] = rv.y;
            r0[i][q * 4 + 2] = rv.z; r0[i][q * 4 + 3] = rv.w;
          }
        }
#pragma unroll
      for (int i = 0; i < 4; ++i)
        if (i < s) {
#pragma unroll
          for (int j = 0; j < 16; ++j)
            h[j] = fmaf(-coefF[i], r0[i][j], h[j]);
        }
      // chunk 1: rows 4..6, reusing r0 registers
#pragma unroll
      for (int i = 4; i < 7; ++i)
        if (i < s) {
#pragma unroll
          for (int q = 0; q < 4; ++q) {
            float4 rv = *reinterpret_cast<const float4*>(
                &G[(size_t)selI[i] * NATOM + lane16 + q * 4]);
            r0[i - 4][q * 4 + 0] = rv.x; r0[i - 4][q * 4 + 1] = rv.y;
            r0[i - 4][q * 4 + 2] = rv.z; r0[i - 4][q * 4 + 3] = rv.w;
          }
        }
#pragma unroll
      for (int i = 4; i < 7; ++i)
        if (i < s) {
#pragma unroll
          for (int j = 0; j < 16; ++j)
            h[j] = fmaf(-coefF[i], r0[i - 4][j], h[j]);
        }
    }
    // ---- wave max of |h| (exact f32; fmaxf ignores NaN-poisoned slots) ----
    float sc[16];
#pragma unroll
    for (int j = 0; j < 16; ++j) sc[j] = fabsf(h[j]);
    float m0 = fmaxf(fmaxf(fmaxf(sc[0], sc[1]), sc[2]), sc[3]);
    float m1 = fmaxf(fmaxf(fmaxf(sc[4], sc[5]), sc[6]), sc[7]);
    float m2 = fmaxf(fmaxf(fmaxf(sc[8], sc[9]), sc[10]), sc[11]);
    float m3 = fmaxf(fmaxf(fmaxf(sc[12], sc[13]), sc[14]), sc[15]);
    const float M = wave_max_bcast(fmaxf(fmaxf(m0, m1), fmaxf(m2, m3)));
    // ---- first-occurrence index among sc==M (ballot; lane-major order) ----
    unsigned cand = NATOM;
#pragma unroll
    for (int j = 0; j < 16; ++j) {
      unsigned idx = (unsigned)(lane16 + j);
      unsigned c = (sc[j] == M) ? idx : (unsigned)NATOM;
      cand = cand < c ? cand : c;
    }
    unsigned long long bal = __ballot(cand != (unsigned)NATOM);
    const int fl = __ffsll(bal) - 1;  // lowest lane holding a candidate
    const int bk = __builtin_amdgcn_readlane((int)cand, fl);  // wave-uniform
    selI[s] = bk;
    const int bl = bk >> 4, bj = bk & 15;

    // hbs: wave-uniform load (memory is never poisoned)
    float hbs;
    if (HBWS) {
      hbs = HB[(size_t)n * NATOM + bk];  // s_load, hidden under chol below
    } else {
      float v = 0.f;
#pragma unroll
      for (int j = 0; j < 16; ++j)
        if (j == bj) v = hb[j];
      hbs = __int_as_float(__builtin_amdgcn_readlane(__float_as_int(v), bl));
    }

    // poison the selected slot: it loses every future argmax (NaN semantics)
#pragma unroll
    for (int j = 0; j < 16; ++j)
      if (j == bj && lane == bl) hb[j] = __builtin_nanf("");

    // ---- Cholesky update: L_{s+1} = [[L, 0], [w^T, corner]] ----
    const float diag = Gd[bk];  // wave-uniform scalar load
    float w[SPAR];
    float sq = 0.f;
#pragma unroll
    for (int i = 0; i < SPAR; ++i)
      if (i < s) {
        float a = G[(size_t)selI[i] * NATOM + bk];  // uniform scalar load
#pragma unroll
        for (int t = 0; t < SPAR; ++t)
          if (t < i) a = fmaf(-Lm[i][t], w[t], a);
        w[i] = a * invL[i];
        sq += w[i] * w[i];
        Lm[s][i] = w[i];
      }
    float cc = diag - sq;
    if (cc < 1e-6f) cc = 1e-6f;  // jnp.clip(..., CHOL_EPS)
    invL[s] = 1.0f / sqrtf(cc);

    // ---- y_s (incremental forward solve) ----
    {
      float a = hbs;
#pragma unroll
      for (int t = 0; t < SPAR; ++t)
        if (t < s) a = fmaf(-Lm[s][t], ysel[t], a);
      ysel[s] = a * invL[s];
    }
    // ---- coef: backward solve L^T x = y ----
#pragma unroll
    for (int i = SPAR - 1; i >= 0; --i)
      if (i <= s) {
        float a = ysel[i];
#pragma unroll
        for (int t = 0; t < SPAR; ++t)
          if (t > i && t <= s) a = fmaf(-Lm[t][i], coefF[t], a);
        coefF[i] = a * invL[i];
      }
  }

  // ---- outputs: recon [n][64], I [n][8], coeffs [n][8] ----
  double r = 0.0;
#pragma unroll
  for (int i = 0; i < SPAR; ++i) {
    float dv = DTW ? Dt[(size_t)selI[i] * DIM + lane]
                   : D[(size_t)lane * NATOM + selI[i]];
    r += (double)coefF[i] * (double)dv;
  }
  out[(size_t)n * DIM + lane] = (float)r;

  float fi = 0.f, fc = 0.f;
#pragma unroll
  for (int i = 0; i < SPAR; ++i)
    if (lane == i) { fi = (float)selI[i]; fc = coefF[i]; }
  if (lane < SPAR) {
    out[(size_t)NPIX * DIM + (size_t)n * SPAR + lane] = fi;
    out[(size_t)NPIX * DIM + (size_t)NPIX * SPAR + (size_t)n * SPAR + lane] = fc;
  }
}

// Standalone gram for the tiny-workspace fallback
__global__ __launch_bounds__(256) void k_gram(const float* __restrict__ D,
                                              float* __restrict__ G,
                                              float* __restrict__ Gd) {
  int k1 = blockIdx.x;
  __shared__ float d1[DIM];
  if (threadIdx.x < DIM) d1[threadIdx.x] = D[(size_t)threadIdx.x * NATOM + k1];
  __syncthreads();
  for (int k2 = threadIdx.x; k2 < NATOM; k2 += 256) {
    double acc = 0.0;
#pragma unroll
    for (int d = 0; d < DIM; ++d)
      acc += (double)d1[d] * (double)D[(size_t)d * NATOM + k2];
    float g = (float)acc;
    if (k2 == k1) {
      g += 1e-4f;
      Gd[k1] = g;
    }
    G[(size_t)k1 * NATOM + k2] = g;
  }
}

extern "C" void kernel_launch(void* const* d_in, const int* in_sizes, int n_in,
                              void* d_out, int out_size, void* d_ws,
                              size_t ws_size, hipStream_t stream) {
  const float* X = (const float*)d_in[0];  // [64, 16384]
  const float* D = (const float*)d_in[1];  // [64, 1024]
  float* out = (float*)d_out;              // [recon | I | coeffs] as fp32
  float* G = (float*)d_ws;                 // 4 MB
  float* Dt = G + (size_t)NATOM * NATOM;   // 256 KB
  float* Gd = Dt + (size_t)NATOM * DIM;    // 4 KB
  float* HB = Gd + NATOM;                  // 64 MB
  const size_t needFull =
      ((size_t)NATOM * NATOM + (size_t)NATOM * DIM + NATOM +
       (size_t)NPIX * NATOM) * sizeof(float);

  if (ws_size >= needFull) {
    k_pre<<<dim3(1344), dim3(256), 0, stream>>>(X, D, G, Dt, Gd, HB);
    k_omp<true, true><<<dim3(NPIX), dim3(64), 0, stream>>>(
        HB, X, D, Dt, G, Gd, out);
  } else {
    k_gram<<<dim3(NATOM), dim3(256), 0, stream>>>(D, G, Gd);
    k_omp<false, false><<<dim3(NPIX), dim3(64), 0, stream>>>(
        nullptr, X, D, nullptr, G, Gd, out);
  }
}

// Round 10
// 110.120 us; speedup vs baseline: 1.1777x; 1.1777x over previous
//
#include <hip/hip_runtime.h>
#include <cmath>

#define NPIX 16384
#define NATOM 1024
#define DIM 64
#define SPAR 8

// ---------------------------------------------------------------------------
// Fused pre-pass, grid-partitioned (1344 blocks):
//   [0,256):    G 64x64 tile (bi,bj) = D^T D + 1e-4 I, fp64 acc (LDS-staged,
//               ascending-d order); Gd diag
//   [256,320):  Dt transpose (each block 1024 contiguous D elems)
//   [320,1344): HB 128n x 128k tile (fp32, 8x8/thread)
// ---------------------------------------------------------------------------
__global__ __launch_bounds__(256) void k_pre(const float* __restrict__ X,
                                             const float* __restrict__ D,
                                             float* __restrict__ G,
                                             float* __restrict__ Dt,
                                             float* __restrict__ Gd,
                                             float* __restrict__ HB) {
  __shared__ float smem[2 * DIM * 128];  // 64 KiB
  const int b = blockIdx.x;
  if (b < 256) {
    // ---- gram tile ----
    const int i0 = (b >> 4) * 64, j0 = (b & 15) * 64;
    float(*sA)[65] = (float(*)[65])smem;                  // D[:, i0..i0+63]
    float(*sB)[65] = (float(*)[65])(smem + DIM * 65);     // D[:, j0..j0+63]
    for (int t = threadIdx.x; t < DIM * 16; t += 256) {
      int d = t >> 4, c4 = (t & 15) * 4;
      *reinterpret_cast<float4*>(&sA[d][c4]) =
          *reinterpret_cast<const float4*>(&D[(size_t)d * NATOM + i0 + c4]);
      *reinterpret_cast<float4*>(&sB[d][c4]) =
          *reinterpret_cast<const float4*>(&D[(size_t)d * NATOM + j0 + c4]);
    }
    __syncthreads();
    const int ty = (threadIdx.x >> 4) * 4;  // row micro-tile
    const int tx = (threadIdx.x & 15) * 4;  // col micro-tile
    double acc[4][4];
#pragma unroll
    for (int ii = 0; ii < 4; ++ii)
#pragma unroll
      for (int jj = 0; jj < 4; ++jj) acc[ii][jj] = 0.0;
    for (int d = 0; d < DIM; ++d) {
      float a[4], bb[4];
#pragma unroll
      for (int ii = 0; ii < 4; ++ii) a[ii] = sA[d][ty + ii];
#pragma unroll
      for (int jj = 0; jj < 4; ++jj) bb[jj] = sB[d][tx + jj];
#pragma unroll
      for (int ii = 0; ii < 4; ++ii)
#pragma unroll
        for (int jj = 0; jj < 4; ++jj)
          acc[ii][jj] += (double)a[ii] * (double)bb[jj];
    }
#pragma unroll
    for (int ii = 0; ii < 4; ++ii)
#pragma unroll
      for (int jj = 0; jj < 4; ++jj) {
        const int k1 = i0 + ty + ii, k2 = j0 + tx + jj;
        float g = (float)acc[ii][jj];
        if (k1 == k2) {
          g += 1e-4f;
          Gd[k1] = g;
        }
        G[(size_t)k1 * NATOM + k2] = g;
      }
  } else if (b < 320) {
    // ---- Dt transpose ----
    const int base = (b - 256) * 1024 + threadIdx.x * 4;
    float4 v = *reinterpret_cast<const float4*>(&D[base]);
    const float vv[4] = {v.x, v.y, v.z, v.w};
#pragma unroll
    for (int e = 0; e < 4; ++e) {
      int idx = base + e;
      Dt[(size_t)(idx & (NATOM - 1)) * DIM + (idx >> 10)] = vv[e];
    }
  } else {
    // ---- HB tile ----
    const int bx = b - 320;
    const int n0 = (bx & 127) * 128, k0 = (bx >> 7) * 128;
    float(*sX)[128] = (float(*)[128])smem;
    float(*sD)[128] = (float(*)[128])(smem + DIM * 128);
    for (int i = threadIdx.x; i < DIM * 32; i += 256) {
      int d = i >> 5, c4 = (i & 31) * 4;
      *reinterpret_cast<float4*>(&sX[d][c4]) =
          *reinterpret_cast<const float4*>(&X[(size_t)d * NPIX + n0 + c4]);
      *reinterpret_cast<float4*>(&sD[d][c4]) =
          *reinterpret_cast<const float4*>(&D[(size_t)d * NATOM + k0 + c4]);
    }
    __syncthreads();
    const int nl = (threadIdx.x & 15) * 8;
    const int kl = (threadIdx.x >> 4) * 8;
    float acc[8][8];
#pragma unroll
    for (int i = 0; i < 8; ++i)
#pragma unroll
      for (int j = 0; j < 8; ++j) acc[i][j] = 0.f;
#pragma unroll 4
    for (int d = 0; d < DIM; ++d) {
      float xv[8], dv[8];
      *reinterpret_cast<float4*>(&xv[0]) = *reinterpret_cast<float4*>(&sX[d][nl]);
      *reinterpret_cast<float4*>(&xv[4]) = *reinterpret_cast<float4*>(&sX[d][nl + 4]);
      *reinterpret_cast<float4*>(&dv[0]) = *reinterpret_cast<float4*>(&sD[d][kl]);
      *reinterpret_cast<float4*>(&dv[4]) = *reinterpret_cast<float4*>(&sD[d][kl + 4]);
#pragma unroll
      for (int i = 0; i < 8; ++i)
#pragma unroll
        for (int j = 0; j < 8; ++j) acc[i][j] = fmaf(xv[i], dv[j], acc[i][j]);
    }
#pragma unroll
    for (int i = 0; i < 8; ++i)
#pragma unroll
      for (int j = 0; j < 2; ++j)
        *reinterpret_cast<float4*>(
            &HB[(size_t)(n0 + nl + i) * NATOM + k0 + kl + j * 4]) =
            *reinterpret_cast<float4*>(&acc[i][j * 4]);
  }
}

// ---------------------------------------------------------------------------
// DPP wave64 max-reduce (VALU latency, no LDS). HW-verified (rounds 6-9).
// ---------------------------------------------------------------------------
template <int CTRL>
__device__ __forceinline__ float dpp_fmax(float x) {
  int s = __builtin_amdgcn_update_dpp(__float_as_int(x), __float_as_int(x),
                                      CTRL, 0xf, 0xf, false);
  return fmaxf(x, __int_as_float(s));
}
__device__ __forceinline__ float wave_max_bcast(float x) {
  x = dpp_fmax<0x111>(x);  // row_shr:1
  x = dpp_fmax<0x112>(x);  // row_shr:2
  x = dpp_fmax<0x114>(x);  // row_shr:4
  x = dpp_fmax<0x118>(x);  // row_shr:8
  x = dpp_fmax<0x142>(x);  // row_bcast:15
  x = dpp_fmax<0x143>(x);  // row_bcast:31
  return __int_as_float(__builtin_amdgcn_readlane(__float_as_int(x), 63));
}

// ---------------------------------------------------------------------------
// Batched OMP: ONE WAVE PER PIXEL, 64-thread blocks, no LDS/barriers.
// Lane owns atoms k = lane*16+j (dwordx4-coalesced G/HB traffic).
// R8 register policy (best measured): all selected G rows PINNED in
// registers (rows[7][16]); beta/argmax is pure-register FMA; vmcnt for the
// new row lands post-solve via end-of-step empty-asm pins.
// Masking: NaN poison of hb (selected atom loses every future argmax:
// fmaxf ignores NaN, |NaN|==M is false).
// Argmax: exact f32 wave max via DPP (abs folded into input modifiers);
// in-lane first-match via descending-j cndmask chain; cross-lane index via
// ballot+ffs+readlane (lane-major order == np.argmax first occurrence).
// hbs/diag/chol-column via wave-uniform scalar loads.
// ---------------------------------------------------------------------------
template <bool HBWS, bool DTW>
__global__ __launch_bounds__(64) void k_omp(const float* __restrict__ HB,
                                            const float* __restrict__ X,
                                            const float* __restrict__ D,
                                            const float* __restrict__ Dt,
                                            const float* __restrict__ G,
                                            const float* __restrict__ Gd,
                                            float* __restrict__ out) {
  const int lane = threadIdx.x & 63;
  const int lane16 = lane * 16;
  const int n = __builtin_amdgcn_readfirstlane(blockIdx.x);

  float hb[16];
  if (HBWS) {
#pragma unroll
    for (int q = 0; q < 4; ++q) {
      float4 v = *reinterpret_cast<const float4*>(
          &HB[(size_t)n * NATOM + lane16 + q * 4]);
      hb[q * 4 + 0] = v.x; hb[q * 4 + 1] = v.y;
      hb[q * 4 + 2] = v.z; hb[q * 4 + 3] = v.w;
    }
  } else {
    double a[16];
#pragma unroll
    for (int j = 0; j < 16; ++j) a[j] = 0.0;
    for (int d = 0; d < DIM; ++d) {
      float xd = X[(size_t)d * NPIX + n];
#pragma unroll
      for (int j = 0; j < 16; ++j)
        a[j] += (double)xd * (double)D[(size_t)d * NATOM + lane16 + j];
    }
#pragma unroll
    for (int j = 0; j < 16; ++j) hb[j] = (float)a[j];
  }
#pragma unroll
  for (int j = 0; j < 16; ++j) asm volatile("" : "+v"(hb[j]));

  int selI[SPAR];  // wave-uniform -> SGPRs
  float rows[SPAR - 1][16];  // rows[i][j] = G[selI[i]][lane16+j], pinned
  float Lm[SPAR][SPAR], invL[SPAR], ysel[SPAR], coefF[SPAR];

#pragma unroll 8
  for (int s = 0; s < SPAR; ++s) {
    // ---- h = hb - sum_i coef_i * rows_i (ascending i, register FMA) ----
    float h[16];
#pragma unroll
    for (int j = 0; j < 16; ++j) {
      float hv = hb[j];
#pragma unroll
      for (int i = 0; i < SPAR - 1; ++i)
        if (i < s) hv = fmaf(-coefF[i], rows[i][j], hv);
      h[j] = hv;
    }
    // ---- wave max of |h| (abs folds into v_max input modifiers) ----
    float m0 = fmaxf(fmaxf(fmaxf(fabsf(h[0]), fabsf(h[1])), fabsf(h[2])), fabsf(h[3]));
    float m1 = fmaxf(fmaxf(fmaxf(fabsf(h[4]), fabsf(h[5])), fabsf(h[6])), fabsf(h[7]));
    float m2 = fmaxf(fmaxf(fmaxf(fabsf(h[8]), fabsf(h[9])), fabsf(h[10])), fabsf(h[11]));
    float m3 = fmaxf(fmaxf(fmaxf(fabsf(h[12]), fabsf(h[13])), fabsf(h[14])), fabsf(h[15]));
    const float M = wave_max_bcast(fmaxf(fmaxf(m0, m1), fmaxf(m2, m3)));
    // ---- in-lane first match (descending j: last write = min j) ----
    unsigned cand = NATOM;
#pragma unroll
    for (int j = 15; j >= 0; --j)
      cand = (fabsf(h[j]) == M) ? (unsigned)(lane16 + j) : cand;
    // ---- cross-lane: lowest lane with a match holds the global min idx ----
    unsigned long long bal = __ballot(cand != (unsigned)NATOM);
    const int fl = __ffsll(bal) - 1;
    const int bk = __builtin_amdgcn_readlane((int)cand, fl);  // wave-uniform
    selI[s] = bk;
    const int bl = bk >> 4, bj = bk & 15;

    // hbs: wave-uniform load from memory (never poisoned)
    float hbs;
    if (HBWS) {
      hbs = HB[(size_t)n * NATOM + bk];  // s_load, hidden under chol below
    } else {
      float v = 0.f;
#pragma unroll
      for (int j = 0; j < 16; ++j)
        if (j == bj) v = hb[j];
      hbs = __int_as_float(__builtin_amdgcn_readlane(__float_as_int(v), bl));
    }

    // poison the selected slot: it loses every future argmax (NaN semantics)
#pragma unroll
    for (int j = 0; j < 16; ++j)
      if (j == bj && lane == bl) hb[j] = __builtin_nanf("");

    // issue new-row fetch (dwordx4 x4); completes during chol/solve below
    if (s < SPAR - 1) {
#pragma unroll
      for (int q = 0; q < 4; ++q) {
        float4 rv = *reinterpret_cast<const float4*>(
            &G[(size_t)bk * NATOM + lane16 + q * 4]);
        rows[s][q * 4 + 0] = rv.x; rows[s][q * 4 + 1] = rv.y;
        rows[s][q * 4 + 2] = rv.z; rows[s][q * 4 + 3] = rv.w;
      }
    }

    // ---- Cholesky update: L_{s+1} = [[L, 0], [w^T, corner]] ----
    const float diag = Gd[bk];  // wave-uniform scalar load
    float w[SPAR];
    float sq = 0.f;
#pragma unroll
    for (int i = 0; i < SPAR; ++i)
      if (i < s) {
        float a = G[(size_t)selI[i] * NATOM + bk];  // uniform scalar load
#pragma unroll
        for (int t = 0; t < SPAR; ++t)
          if (t < i) a = fmaf(-Lm[i][t], w[t], a);
        w[i] = a * invL[i];
        sq += w[i] * w[i];
        Lm[s][i] = w[i];
      }
    float cc = diag - sq;
    if (cc < 1e-6f) cc = 1e-6f;  // jnp.clip(..., CHOL_EPS)
    invL[s] = 1.0f / sqrtf(cc);  // Lm diag never stored (only invL is read)

    // ---- y_s (incremental forward solve) ----
    {
      float a = hbs;
#pragma unroll
      for (int t = 0; t < SPAR; ++t)
        if (t < s) a = fmaf(-Lm[s][t], ysel[t], a);
      ysel[s] = a * invL[s];
    }
    // ---- coef: backward solve L^T x = y ----
#pragma unroll
    for (int i = SPAR - 1; i >= 0; --i)
      if (i <= s) {
        float a = ysel[i];
#pragma unroll
        for (int t = 0; t < SPAR; ++t)
          if (t > i && t <= s) a = fmaf(-Lm[t][i], coefF[t], a);
        coefF[i] = a * invL[i];
      }

    // pin the fetched row: forces residency; waitcnt lands here (post-solve)
    if (s < SPAR - 1) {
#pragma unroll
      for (int j = 0; j < 16; ++j) asm volatile("" : "+v"(rows[s][j]));
    }
  }

  // ---- outputs: recon [n][64], I [n][8], coeffs [n][8] ----
  double r = 0.0;
#pragma unroll
  for (int i = 0; i < SPAR; ++i) {
    float dv = DTW ? Dt[(size_t)selI[i] * DIM + lane]
                   : D[(size_t)lane * NATOM + selI[i]];
    r += (double)coefF[i] * (double)dv;
  }
  out[(size_t)n * DIM + lane] = (float)r;

  float fi = 0.f, fc = 0.f;
#pragma unroll
  for (int i = 0; i < SPAR; ++i)
    if (lane == i) { fi = (float)selI[i]; fc = coefF[i]; }
  if (lane < SPAR) {
    out[(size_t)NPIX * DIM + (size_t)n * SPAR + lane] = fi;
    out[(size_t)NPIX * DIM + (size_t)NPIX * SPAR + (size_t)n * SPAR + lane] = fc;
  }
}

// Standalone gram for the tiny-workspace fallback
__global__ __launch_bounds__(256) void k_gram(const float* __restrict__ D,
                                              float* __restrict__ G,
                                              float* __restrict__ Gd) {
  int k1 = blockIdx.x;
  __shared__ float d1[DIM];
  if (threadIdx.x < DIM) d1[threadIdx.x] = D[(size_t)threadIdx.x * NATOM + k1];
  __syncthreads();
  for (int k2 = threadIdx.x; k2 < NATOM; k2 += 256) {
    double acc = 0.0;
#pragma unroll
    for (int d = 0; d < DIM; ++d)
      acc += (double)d1[d] * (double)D[(size_t)d * NATOM + k2];
    float g = (float)acc;
    if (k2 == k1) {
      g += 1e-4f;
      Gd[k1] = g;
    }
    G[(size_t)k1 * NATOM + k2] = g;
  }
}

extern "C" void kernel_launch(void* const* d_in, const int* in_sizes, int n_in,
                              void* d_out, int out_size, void* d_ws,
                              size_t ws_size, hipStream_t stream) {
  const float* X = (const float*)d_in[0];  // [64, 16384]
  const float* D = (const float*)d_in[1];  // [64, 1024]
  float* out = (float*)d_out;              // [recon | I | coeffs] as fp32
  float* G = (float*)d_ws;                 // 4 MB
  float* Dt = G + (size_t)NATOM * NATOM;   // 256 KB
  float* Gd = Dt + (size_t)NATOM * DIM;    // 4 KB
  float* HB = Gd + NATOM;                  // 64 MB
  const size_t needFull =
      ((size_t)NATOM * NATOM + (size_t)NATOM * DIM + NATOM +
       (size_t)NPIX * NATOM) * sizeof(float);

  if (ws_size >= needFull) {
    k_pre<<<dim3(1344), dim3(256), 0, stream>>>(X, D, G, Dt, Gd, HB);
    k_omp<true, true><<<dim3(NPIX), dim3(64), 0, stream>>>(
        HB, X, D, Dt, G, Gd, out);
  } else {
    k_gram<<<dim3(NATOM), dim3(256), 0, stream>>>(D, G, Gd);
    k_omp<false, false><<<dim3(NPIX), dim3(64), 0, stream>>>(
        nullptr, X, D, nullptr, G, Gd, out);
  }
}